// Round 7
// baseline (51.436 us; speedup 1.0000x reference)
//
#include <hip/hip_runtime.h>

// Geometry (from reference): B=4, C=8, D=48, H=128, W=160
#define HW    20480      // H*W
#define DHW   983040     // D*H*W (channel stride, floats)
#define CDHW  7864320    // C*D*H*W (batch stride, floats)
#define NPIX  81920      // B*H*W
#define SLAB  2048       // pixels per block task
#define NSLAB 10         // HW / SLAB
#define DSTEP 8          // d-slices per block task
#define NCHNK 6          // 48 / DSTEP
#define NBLK  (4 * NSLAB * NCHNK)   // 240 blocks

typedef _Float16 half2v __attribute__((ext_vector_type(2)));

// Folded weights (BN absorbed), f16 pairs as uint bit patterns.
__device__ unsigned g_w0u[64];   // [o][i] o<16, i<4
__device__ float    g_b0[16];
__device__ unsigned g_w1u[64];   // [j][i] j<8,  i<8
__device__ float    g_b1[8];
__device__ unsigned g_w2u[4];
__device__ float    g_bias2;

static __device__ __forceinline__ float dot2(half2v a, half2v b, float c) {
#if __has_builtin(__builtin_amdgcn_fdot2)
    return __builtin_amdgcn_fdot2(a, b, c, false);
#else
    return fmaf((float)a.x, (float)b.x, fmaf((float)a.y, (float)b.y, c));
#endif
}
static __device__ __forceinline__ float dot2u(half2v a, unsigned wb, float c) {
    return dot2(a, __builtin_bit_cast(half2v, wb), c);
}
static __device__ __forceinline__ half2v pk(float a, float b) {
#if __has_builtin(__builtin_amdgcn_cvt_pkrtz)
    return __builtin_bit_cast(half2v, __builtin_amdgcn_cvt_pkrtz(a, b));
#else
    half2v h; h.x = (_Float16)a; h.y = (_Float16)b; return h;
#endif
}
static __device__ __forceinline__ unsigned pku(float a, float b) {
    return __builtin_bit_cast(unsigned, pk(a, b));
}

// Order-preserving bijection float -> uint (atomicMax == fmax).
static __device__ __forceinline__ unsigned enc(float f) {
    unsigned u = __float_as_uint(f);
    return (u & 0x80000000u) ? ~u : (u | 0x80000000u);
}
static __device__ __forceinline__ float dec(unsigned u) {
    unsigned v = (u & 0x80000000u) ? (u & 0x7FFFFFFFu) : ~u;
    return __uint_as_float(v);
}

// 16B-per-lane async global->LDS (dest = uniform base + lane*16).
static __device__ __forceinline__ void gload_lds16(const float* g, float* l) {
    __builtin_amdgcn_global_load_lds(
        (const __attribute__((address_space(1))) unsigned int*)g,
        (__attribute__((address_space(3))) unsigned int*)l,
        16, 0, 0);
}

__global__ void fold_kernel(const float* __restrict__ w0, const float* __restrict__ g0,
                            const float* __restrict__ b0, const float* __restrict__ m0,
                            const float* __restrict__ v0,
                            const float* __restrict__ w1, const float* __restrict__ g1,
                            const float* __restrict__ b1, const float* __restrict__ m1,
                            const float* __restrict__ v1,
                            const float* __restrict__ w2, const float* __restrict__ bias2)
{
    int t = threadIdx.x;
    if (t < 16) {
        float sc = g0[t] * rsqrtf(v0[t] + 1e-5f);
        for (int i = 0; i < 4; ++i)
            g_w0u[t * 4 + i] = pku(w0[t * 8 + 2 * i] * sc, w0[t * 8 + 2 * i + 1] * sc);
        g_b0[t] = b0[t] - m0[t] * sc;
    } else if (t < 24) {
        int j = t - 16;
        float sc = g1[j] * rsqrtf(v1[j] + 1e-5f);
        for (int i = 0; i < 8; ++i)
            g_w1u[j * 8 + i] = pku(w1[j * 16 + 2 * i] * sc, w1[j * 16 + 2 * i + 1] * sc);
        g_b1[j] = b1[j] - m1[j] * sc;
    } else if (t == 24) {
        for (int i = 0; i < 4; ++i)
            g_w2u[i] = pku(w2[2 * i], w2[2 * i + 1]);
        g_bias2 = bias2[0];
    }
}

__global__ __launch_bounds__(512, 1)
void mlp_kernel(const float* __restrict__ x, unsigned* __restrict__ outu)
{
    // LDS: double-buffered x slabs + folded weights.
    __shared__ __align__(16) float    lx[2][8][SLAB];   // 128 KB
    __shared__ __align__(16) unsigned lw0[64];
    __shared__            float       lb0[16];
    __shared__ __align__(16) unsigned lw1[64];
    __shared__            float       lb1[8];
    __shared__ __align__(16) unsigned lw2[4];
    __shared__            float       lb2;

    const int tid  = threadIdx.x;
    const int lane = tid & 63;
    const int wv   = tid >> 6;          // 0..7 == channel this wave stages

    // Task decode: 240 = 4 batches x 10 slabs x 6 chunks.
    const int t     = blockIdx.x;
    const int batch = t / (NSLAB * NCHNK);
    const int r     = t - batch * (NSLAB * NCHNK);
    const int slab  = r / NCHNK;
    const int chunk = r - slab * NCHNK;
    const float* xb = x + (size_t)batch * CDHW + (size_t)(chunk * DSTEP) * HW + slab * SLAB;

    // Copy folded weights into LDS (broadcast-read later).
    if (tid < 64)            lw0[tid]       = g_w0u[tid];
    else if (tid < 128)      lw1[tid - 64]  = g_w1u[tid - 64];
    else if (tid < 144)      lb0[tid - 128] = g_b0[tid - 128];
    else if (tid < 152)      lb1[tid - 144] = g_b1[tid - 144];
    else if (tid < 156)      lw2[tid - 152] = g_w2u[tid - 152];
    else if (tid == 156)     lb2            = g_bias2;

    // Stage slice dd into buffer buf: wave wv streams channel wv (8 KB, 8x1KB instrs).
#define STAGE(buf, dd)                                                          \
    {                                                                           \
        const float* _src = xb + (size_t)(dd) * HW + (size_t)wv * DHW + lane*4; \
        float* _dst = &lx[buf][wv][0];                                          \
        _Pragma("unroll")                                                       \
        for (int i = 0; i < 8; ++i)                                             \
            gload_lds16(_src + i * 256, _dst + i * 256);                        \
    }

    STAGE(0, 0)
    __syncthreads();   // weights in LDS + slice 0 staged

    float maxv[4];
#pragma unroll
    for (int k = 0; k < 4; ++k) maxv[k] = -1e30f;

    for (int dd = 0; dd < DSTEP; ++dd) {
        const int buf = dd & 1;
        if (dd + 1 < DSTEP) STAGE(buf ^ 1, dd + 1)

        // ---- load this thread's 4 px x 8 ch from LDS ----
        float ld[8][4];
#pragma unroll
        for (int c = 0; c < 8; ++c) {
            float4 v = *(const float4*)&lx[buf][c][tid * 4];
            ld[c][0] = v.x; ld[c][1] = v.y; ld[c][2] = v.z; ld[c][3] = v.w;
        }
        // pack inputs: xh[px][i] = channels 2i,2i+1
        half2v xh[4][4];
#pragma unroll
        for (int px = 0; px < 4; ++px)
#pragma unroll
            for (int i = 0; i < 4; ++i)
                xh[px][i] = pk(ld[2 * i][px], ld[2 * i + 1][px]);

        // ---- layer 0: 8 -> 16, relu, pack pairs ----
        unsigned hh[4][8];   // h0 packed f16 pairs
#pragma unroll
        for (int op = 0; op < 8; ++op) {
            uint4 wA = *(const uint4*)&lw0[(2 * op) * 4];
            uint4 wB = *(const uint4*)&lw0[(2 * op + 1) * 4];
            float bA = lb0[2 * op], bB = lb0[2 * op + 1];
#pragma unroll
            for (int px = 0; px < 4; ++px) {
                float a = bA;
                a = dot2u(xh[px][0], wA.x, a); a = dot2u(xh[px][1], wA.y, a);
                a = dot2u(xh[px][2], wA.z, a); a = dot2u(xh[px][3], wA.w, a);
                float b = bB;
                b = dot2u(xh[px][0], wB.x, b); b = dot2u(xh[px][1], wB.y, b);
                b = dot2u(xh[px][2], wB.z, b); b = dot2u(xh[px][3], wB.w, b);
                hh[px][op] = pku(fmaxf(a, 0.f), fmaxf(b, 0.f));
            }
        }

        // ---- layer 1: 16 -> 8, relu, pack pairs ----
        unsigned hq[4][4];
#pragma unroll
        for (int jp = 0; jp < 4; ++jp) {
            uint4 wA0 = *(const uint4*)&lw1[(2 * jp) * 8];
            uint4 wA1 = *(const uint4*)&lw1[(2 * jp) * 8 + 4];
            uint4 wB0 = *(const uint4*)&lw1[(2 * jp + 1) * 8];
            uint4 wB1 = *(const uint4*)&lw1[(2 * jp + 1) * 8 + 4];
            float bA = lb1[2 * jp], bB = lb1[2 * jp + 1];
#pragma unroll
            for (int px = 0; px < 4; ++px) {
                half2v h0 = __builtin_bit_cast(half2v, hh[px][0]);
                half2v h1 = __builtin_bit_cast(half2v, hh[px][1]);
                half2v h2 = __builtin_bit_cast(half2v, hh[px][2]);
                half2v h3 = __builtin_bit_cast(half2v, hh[px][3]);
                half2v h4 = __builtin_bit_cast(half2v, hh[px][4]);
                half2v h5 = __builtin_bit_cast(half2v, hh[px][5]);
                half2v h6 = __builtin_bit_cast(half2v, hh[px][6]);
                half2v h7 = __builtin_bit_cast(half2v, hh[px][7]);
                float a = bA;
                a = dot2u(h0, wA0.x, a); a = dot2u(h1, wA0.y, a);
                a = dot2u(h2, wA0.z, a); a = dot2u(h3, wA0.w, a);
                a = dot2u(h4, wA1.x, a); a = dot2u(h5, wA1.y, a);
                a = dot2u(h6, wA1.z, a); a = dot2u(h7, wA1.w, a);
                float b = bB;
                b = dot2u(h0, wB0.x, b); b = dot2u(h1, wB0.y, b);
                b = dot2u(h2, wB0.z, b); b = dot2u(h3, wB0.w, b);
                b = dot2u(h4, wB1.x, b); b = dot2u(h5, wB1.y, b);
                b = dot2u(h6, wB1.z, b); b = dot2u(h7, wB1.w, b);
                hq[px][jp] = pku(fmaxf(a, 0.f), fmaxf(b, 0.f));
            }
        }

        // ---- layer 2: 8 -> 1, running max ----
        {
            uint4 w2 = *(const uint4*)&lw2[0];
            float b2 = lb2;
#pragma unroll
            for (int px = 0; px < 4; ++px) {
                float a = b2;
                a = dot2u(__builtin_bit_cast(half2v, hq[px][0]), w2.x, a);
                a = dot2u(__builtin_bit_cast(half2v, hq[px][1]), w2.y, a);
                a = dot2u(__builtin_bit_cast(half2v, hq[px][2]), w2.z, a);
                a = dot2u(__builtin_bit_cast(half2v, hq[px][3]), w2.w, a);
                maxv[px] = fmaxf(maxv[px], a);
            }
        }

        __syncthreads();   // staged buffer ready; current buffer free for reuse
    }
#undef STAGE

    // Merge partial d-max into output (monotone-uint atomicMax).
    unsigned* po = outu + (size_t)batch * HW + slab * SLAB + tid * 4;
#pragma unroll
    for (int k = 0; k < 4; ++k) atomicMax(po + k, enc(maxv[k]));
}

// Decode -> sigmoid in place.
__global__ __launch_bounds__(256)
void finish_kernel(unsigned* __restrict__ outu)
{
    int i = blockIdx.x * 256 + threadIdx.x;
    if (i < NPIX) {
        float m = dec(outu[i]);
        ((float*)outu)[i] = 1.0f / (1.0f + __expf(-m));
    }
}

extern "C" void kernel_launch(void* const* d_in, const int* in_sizes, int n_in,
                              void* d_out, int out_size, void* d_ws, size_t ws_size,
                              hipStream_t stream) {
    const float* x1 = (const float*)d_in[0];
    unsigned* outu = (unsigned*)d_out;

    // enc(finite) > 0, so zero is a safe "-inf" for atomicMax.
    hipMemsetAsync(d_out, 0, (size_t)NPIX * 4, stream);

    fold_kernel<<<1, 64, 0, stream>>>(
        (const float*)d_in[1], (const float*)d_in[2], (const float*)d_in[3],
        (const float*)d_in[4], (const float*)d_in[5],
        (const float*)d_in[6], (const float*)d_in[7], (const float*)d_in[8],
        (const float*)d_in[9], (const float*)d_in[10],
        (const float*)d_in[11], (const float*)d_in[12]);

    mlp_kernel<<<NBLK, 512, 0, stream>>>(x1, outu);
    finish_kernel<<<(NPIX + 255) / 256, 256, 0, stream>>>(outu);
}

// Round 8
// 50.797 us; speedup vs baseline: 1.0126x; 1.0126x over previous
//
#include <hip/hip_runtime.h>

// Geometry (from reference): B=4, C=8, D=48, H=128, W=160
#define HW    20480      // H*W
#define DHW   983040     // D*H*W (channel stride, floats)
#define CDHW  7864320    // C*D*H*W (batch stride, floats)
#define NPIX  81920      // B*H*W
#define SLAB  1024       // pixels per block task
#define NSLAB 20         // HW / SLAB
#define DSTEP 8          // d-slices per block task
#define NCHNK 6          // 48 / DSTEP
#define NBLK  (4 * NSLAB * NCHNK)   // 480 blocks

// Folded weights (BN absorbed), plain f32.
__device__ float g_w0f[128];   // [o][c] o<16, c<8
__device__ float g_b0[16];
__device__ float g_w1f[128];   // [j][o] j<8, o<16
__device__ float g_b1[8];
__device__ float g_w2f[8];
__device__ float g_bias2;

// Order-preserving bijection float -> uint (atomicMax == fmax).
static __device__ __forceinline__ unsigned enc(float f) {
    unsigned u = __float_as_uint(f);
    return (u & 0x80000000u) ? ~u : (u | 0x80000000u);
}
static __device__ __forceinline__ float dec(unsigned u) {
    unsigned v = (u & 0x80000000u) ? (u & 0x7FFFFFFFu) : ~u;
    return __uint_as_float(v);
}

// 16B-per-lane async global->LDS (dest = wave-uniform base + lane*16).
static __device__ __forceinline__ void gload_lds16(const float* g, float* l) {
    __builtin_amdgcn_global_load_lds(
        (const __attribute__((address_space(1))) unsigned int*)g,
        (__attribute__((address_space(3))) unsigned int*)l,
        16, 0, 0);
}

__global__ void fold_kernel(const float* __restrict__ w0, const float* __restrict__ g0,
                            const float* __restrict__ b0, const float* __restrict__ m0,
                            const float* __restrict__ v0,
                            const float* __restrict__ w1, const float* __restrict__ g1,
                            const float* __restrict__ b1, const float* __restrict__ m1,
                            const float* __restrict__ v1,
                            const float* __restrict__ w2, const float* __restrict__ bias2)
{
    int t = threadIdx.x;
    if (t < 16) {
        float sc = g0[t] * rsqrtf(v0[t] + 1e-5f);
        for (int c = 0; c < 8; ++c) g_w0f[t * 8 + c] = w0[t * 8 + c] * sc;
        g_b0[t] = b0[t] - m0[t] * sc;
    } else if (t < 24) {
        int j = t - 16;
        float sc = g1[j] * rsqrtf(v1[j] + 1e-5f);
        for (int o = 0; o < 16; ++o) g_w1f[j * 16 + o] = w1[j * 16 + o] * sc;
        g_b1[j] = b1[j] - m1[j] * sc;
    } else if (t == 24) {
        for (int c = 0; c < 8; ++c) g_w2f[c] = w2[c];
        g_bias2 = bias2[0];
    }
}

__global__ __launch_bounds__(256, 2)
void mlp_kernel(const float* __restrict__ x, unsigned* __restrict__ outu)
{
    // LDS: double-buffered x slabs (64 KB) + f32 weights (~1.2 KB).
    __shared__ __align__(16) float lx[2][8][SLAB];
    __shared__ __align__(16) float lw0[128];
    __shared__ float lb0[16];
    __shared__ __align__(16) float lw1[128];
    __shared__ float lb1[8];
    __shared__ __align__(16) float lw2[8];
    __shared__ float lb2s;

    const int tid  = threadIdx.x;
    const int lane = tid & 63;
    const int wv   = tid >> 6;          // 0..3; wave stages channels 2wv, 2wv+1

    // Task decode: 480 = 4 batches x 20 slabs x 6 chunks.
    const int t     = blockIdx.x;
    const int batch = t / (NSLAB * NCHNK);
    const int r     = t - batch * (NSLAB * NCHNK);
    const int slab  = r / NCHNK;
    const int chunk = r - slab * NCHNK;
    const float* xb = x + (size_t)batch * CDHW + (size_t)(chunk * DSTEP) * HW + slab * SLAB;

    // Weights -> LDS (broadcast-read later; wave-uniform addresses).
    if (tid < 128)       lw0[tid]       = g_w0f[tid];
    else                 lw1[tid - 128] = g_w1f[tid - 128];
    if (tid < 16)        lb0[tid]       = g_b0[tid];
    if (tid < 8)         lb1[tid]       = g_b1[tid];
    if (tid < 8)         lw2[tid]       = g_w2f[tid];
    if (tid == 0)        lb2s           = g_bias2;

    // Stage slice dd into buffer buf: wave wv streams channels 2wv,2wv+1 (4 KB each).
#define STAGE(buf, dd)                                                            \
    {                                                                             \
        const float* _s0 = xb + (size_t)(dd) * HW + (size_t)(2 * wv) * DHW + lane * 4; \
        const float* _s1 = _s0 + DHW;                                             \
        float* _d0 = &lx[buf][2 * wv][0];                                         \
        float* _d1 = &lx[buf][2 * wv + 1][0];                                     \
        _Pragma("unroll")                                                         \
        for (int i = 0; i < 4; ++i) gload_lds16(_s0 + i * 256, _d0 + i * 256);    \
        _Pragma("unroll")                                                         \
        for (int i = 0; i < 4; ++i) gload_lds16(_s1 + i * 256, _d1 + i * 256);    \
    }

    STAGE(0, 0)
    __syncthreads();   // weights in LDS + slice 0 staged

    float maxv[4];
#pragma unroll
    for (int k = 0; k < 4; ++k) maxv[k] = -1e30f;

    for (int dd = 0; dd < DSTEP; ++dd) {
        const int buf = dd & 1;
        if (dd + 1 < DSTEP) STAGE(buf ^ 1, dd + 1)

        // ---- this thread's 4 px x 8 ch from LDS ----
        float xr[8][4];
#pragma unroll
        for (int c = 0; c < 8; ++c) {
            float4 v = *(const float4*)&lx[buf][c][tid * 4];
            xr[c][0] = v.x; xr[c][1] = v.y; xr[c][2] = v.z; xr[c][3] = v.w;
        }

        // ---- layer 0: 8 -> 16, relu (f32 fma, weights broadcast from LDS) ----
        float h0[16][4];
#pragma unroll
        for (int o = 0; o < 16; ++o) {
            float4 wA = *(const float4*)&lw0[o * 8];
            float4 wB = *(const float4*)&lw0[o * 8 + 4];
            float  bA = lb0[o];
#pragma unroll
            for (int px = 0; px < 4; ++px) {
                float a = bA;
                a = fmaf(wA.x, xr[0][px], a); a = fmaf(wA.y, xr[1][px], a);
                a = fmaf(wA.z, xr[2][px], a); a = fmaf(wA.w, xr[3][px], a);
                a = fmaf(wB.x, xr[4][px], a); a = fmaf(wB.y, xr[5][px], a);
                a = fmaf(wB.z, xr[6][px], a); a = fmaf(wB.w, xr[7][px], a);
                h0[o][px] = fmaxf(a, 0.0f);
            }
        }

        // ---- layer 1: 16 -> 8, relu ----
        float h1[8][4];
#pragma unroll
        for (int j = 0; j < 8; ++j) {
            float4 w0v = *(const float4*)&lw1[j * 16];
            float4 w1v = *(const float4*)&lw1[j * 16 + 4];
            float4 w2v = *(const float4*)&lw1[j * 16 + 8];
            float4 w3v = *(const float4*)&lw1[j * 16 + 12];
            float  bj  = lb1[j];
#pragma unroll
            for (int px = 0; px < 4; ++px) {
                float a = bj;
                a = fmaf(w0v.x, h0[0][px], a);  a = fmaf(w0v.y, h0[1][px], a);
                a = fmaf(w0v.z, h0[2][px], a);  a = fmaf(w0v.w, h0[3][px], a);
                a = fmaf(w1v.x, h0[4][px], a);  a = fmaf(w1v.y, h0[5][px], a);
                a = fmaf(w1v.z, h0[6][px], a);  a = fmaf(w1v.w, h0[7][px], a);
                a = fmaf(w2v.x, h0[8][px], a);  a = fmaf(w2v.y, h0[9][px], a);
                a = fmaf(w2v.z, h0[10][px], a); a = fmaf(w2v.w, h0[11][px], a);
                a = fmaf(w3v.x, h0[12][px], a); a = fmaf(w3v.y, h0[13][px], a);
                a = fmaf(w3v.z, h0[14][px], a); a = fmaf(w3v.w, h0[15][px], a);
                h1[j][px] = fmaxf(a, 0.0f);
            }
        }

        // ---- layer 2: 8 -> 1, running max ----
        {
            float4 wA = *(const float4*)&lw2[0];
            float4 wB = *(const float4*)&lw2[4];
#pragma unroll
            for (int px = 0; px < 4; ++px) {
                float a = 0.0f;
                a = fmaf(wA.x, h1[0][px], a); a = fmaf(wA.y, h1[1][px], a);
                a = fmaf(wA.z, h1[2][px], a); a = fmaf(wA.w, h1[3][px], a);
                a = fmaf(wB.x, h1[4][px], a); a = fmaf(wB.y, h1[5][px], a);
                a = fmaf(wB.z, h1[6][px], a); a = fmaf(wB.w, h1[7][px], a);
                maxv[px] = fmaxf(maxv[px], a);
            }
        }

        __syncthreads();   // next staged buffer complete; current buffer reusable
    }
#undef STAGE

    // Merge partial d-max into output (monotone-uint atomicMax). bias2 added in finish.
    unsigned* po = outu + (size_t)batch * HW + slab * SLAB + tid * 4;
#pragma unroll
    for (int k = 0; k < 4; ++k) atomicMax(po + k, enc(maxv[k]));
}

// Decode -> +bias2 -> sigmoid, in place.
__global__ __launch_bounds__(256)
void finish_kernel(unsigned* __restrict__ outu)
{
    int i = blockIdx.x * 256 + threadIdx.x;
    if (i < NPIX) {
        float m = dec(outu[i]) + g_bias2;
        ((float*)outu)[i] = 1.0f / (1.0f + __expf(-m));
    }
}

extern "C" void kernel_launch(void* const* d_in, const int* in_sizes, int n_in,
                              void* d_out, int out_size, void* d_ws, size_t ws_size,
                              hipStream_t stream) {
    const float* x1 = (const float*)d_in[0];
    unsigned* outu = (unsigned*)d_out;

    // enc(finite) > 0, so zero is a safe "-inf" for atomicMax.
    hipMemsetAsync(d_out, 0, (size_t)NPIX * 4, stream);

    fold_kernel<<<1, 64, 0, stream>>>(
        (const float*)d_in[1], (const float*)d_in[2], (const float*)d_in[3],
        (const float*)d_in[4], (const float*)d_in[5],
        (const float*)d_in[6], (const float*)d_in[7], (const float*)d_in[8],
        (const float*)d_in[9], (const float*)d_in[10],
        (const float*)d_in[11], (const float*)d_in[12]);

    mlp_kernel<<<NBLK, 256, 0, stream>>>(x1, outu);
    finish_kernel<<<(NPIX + 255) / 256, 256, 0, stream>>>(outu);
}